// Round 5
// baseline (377.777 us; speedup 1.0000x reference)
//
#include <hip/hip_runtime.h>
#include <stdint.h>

#define DMODEL 2048
#define NHEADS 32
#define NGRP 8
#define DKH 64
#define BATCH 2
#define SEQ 2048
#define MTOT (BATCH*SEQ)   // 4096

typedef unsigned short u16;
typedef __bf16 bf16x8 __attribute__((ext_vector_type(8)));
typedef float f32x4 __attribute__((ext_vector_type(4)));
typedef _Float16 f16x4 __attribute__((ext_vector_type(4)));
typedef _Float16 f16x8 __attribute__((ext_vector_type(8)));

#define QSCALE 0.18033688011112042f   // (1/8) * log2(e): softmax in exp2 domain

__device__ __forceinline__ u16 f2bf(float f){
    uint32_t x = __float_as_uint(f);
    x += 0x7FFFu + ((x >> 16) & 1u);   // RNE; inputs are finite
    return (u16)(x >> 16);
}

__device__ __forceinline__ void gld_lds16(const u16* g, u16* l){
    __builtin_amdgcn_global_load_lds(
        (const __attribute__((address_space(1))) uint32_t*)g,
        (__attribute__((address_space(3))) uint32_t*)l, 16, 0, 0);
}

// ---------------- conversion kernels ----------------

__global__ void cvt_x_kern(const float* __restrict__ x, u16* __restrict__ xb){
    int i = (blockIdx.x * 256 + threadIdx.x) * 4;
    float4 v = *(const float4*)(x + i);
    uint32_t lo = (uint32_t)f2bf(v.x) | ((uint32_t)f2bf(v.y) << 16);
    uint32_t hi = (uint32_t)f2bf(v.z) | ((uint32_t)f2bf(v.w) << 16);
    *(uint2*)(xb + i) = make_uint2(lo, hi);
}

// all 4 weights [K=2048][N] fp32 -> WT [N][K] bf16, fused into one launch
__global__ void cvt_wT_all(const float* __restrict__ Wq, const float* __restrict__ Wk,
                           const float* __restrict__ Wv, const float* __restrict__ Wo,
                           u16* __restrict__ WqT, u16* __restrict__ WkT,
                           u16* __restrict__ WvT, u16* __restrict__ WoT){
    __shared__ float t[32][33];
    int bx = blockIdx.x;
    const float* W; u16* T; int N; int cx;
    if (bx < 64)      { W = Wq; T = WqT; N = 2048; cx = bx; }
    else if (bx < 80) { W = Wk; T = WkT; N = 512;  cx = bx - 64; }
    else if (bx < 96) { W = Wv; T = WvT; N = 512;  cx = bx - 80; }
    else              { W = Wo; T = WoT; N = 2048; cx = bx - 96; }
    int tx = threadIdx.x & 31, ty = threadIdx.x >> 5;
    int n0 = cx * 32, k0 = blockIdx.y * 32;
#pragma unroll
    for (int i = 0; i < 4; i++)
        t[ty*4+i][tx] = W[(size_t)(k0 + ty*4 + i) * N + n0 + tx];
    __syncthreads();
#pragma unroll
    for (int i = 0; i < 4; i++)
        T[(size_t)(n0 + ty*4 + i) * DMODEL + k0 + tx] = f2bf(t[tx][ty*4+i]);
}

// ---------------- 8-phase 256x256 NT GEMM (guide T2+T3+T4+T5 template) --------------
// C = A[M][K] * Bt[N][K]^T + bias, K=2048 fixed. 512 thr = 8 waves (2M x 4N), per-wave
// output 128x64, acc[8][4] f32x4 = 128 VGPR. K is consumed in 32-deep "sub-slabs";
// LDS = 4 slots x (A 256x32 + B 256x32) = 128 KiB (2dbuf x 2half).
// Schedule (8 phases per 2 k-tiles; phase = (slot, nh)):
//   phase: {ds_read frags (nh==0: 8 A-frags + 2 B; nh==1: 2 B) | stage 2 gld_lds
//           (one 128-row part of a slab 3-4 phases ahead) -> lgkmcnt(0) -> barrier ->
//           setprio(1) -> 16 MFMA -> setprio(0)}
//   vmcnt(8) at odd phases ONLY (counted, never 0 in main loop): slab u's 4 loads are
//   confirmed exactly when 8 newer loads (2 slabs) are outstanding. lgkmcnt(0) BEFORE
//   the barrier => a slot's readers are drained before any wave can overwrite it after
//   the barrier (race-free by construction). Epilogue iteration peeled: vmcnt 8->4->0.
// LDS swizzle: chunk(16B) ^= (row>>1)&3, applied on the GLOBAL source (staging dest
// stays linear for global_load_lds, m173/m104) and on the ds_read address: every
// b128 read is max 2-way bank aliased = free (m136).
// EPI 3: fused QKV epilogue (Q*QSCALE bf16 [b][h][s][d]; K bf16 [b][g][s][d];
//        V^T f16 [b][g][d][s'] with the flash PV k-slot permutation in s').
// EPI 2: fp32 row-major + bias.
template<int EPI>
__global__ __launch_bounds__(512, 2) void gemm_nt8(
    const u16* __restrict__ A, const u16* __restrict__ Bt,
    const float* __restrict__ bias0, const float* __restrict__ bias1, const float* __restrict__ bias2,
    void* __restrict__ out0, void* __restrict__ out1, void* __restrict__ out2, int Kn)
{
    __shared__ alignas(16) u16 Asub[4][8192];   // 4 slots x 256 rows x 32 elems = 64 KiB
    __shared__ alignas(16) u16 Bsub[4][8192];   // 64 KiB
    const int tid = threadIdx.x, w = tid >> 6, lane = tid & 63;
    const int quad = lane >> 4, l16 = lane & 15;
    const int wm = w >> 2, wn = w & 3;

    // T1: XCD-bijective chunked swizzle on the flattened block id (nwg % 8 == 0 here)
    int bid = blockIdx.y * gridDim.x + blockIdx.x;
    int nwg = gridDim.x * gridDim.y;
    int cpx = nwg >> 3;
    int sbid = (bid & 7) * cpx + (bid >> 3);
    int bx = sbid % gridDim.x, by = sbid / gridDim.x;
    const int m0 = bx * 256, n0 = by * 256;

    // staging thread map: row = i*128 + w*16 + (lane>>2), 16B chunk c = lane&3
    const int srow = w*16 + (lane >> 2);
    const int sc   = lane & 3;
    const int gc   = sc ^ ((srow >> 1) & 3);        // inverse read-swizzle on global src
    const u16* gA = A  + (size_t)(m0 + srow) * Kn + gc*8;
    const u16* gB = Bt + (size_t)(n0 + srow) * Kn + gc*8;

    // frag-read swizzled chunk (row = 16*X + l16 -> (row>>1)&3 == (l16>>1)&3)
    const int swc = (quad ^ ((l16 >> 1) & 3)) * 8;

    bf16x8 af[8], bfr[2];
    f32x4 acc[8][4] = {};

#define STGA(slot, kk) do{ \
        gld_lds16(gA + (kk),                  &Asub[slot][w*512]); \
        gld_lds16(gA + (kk) + (size_t)128*Kn, &Asub[slot][4096 + w*512]); }while(0)
#define STGB(slot, kk) do{ \
        gld_lds16(gB + (kk),                  &Bsub[slot][w*512]); \
        gld_lds16(gB + (kk) + (size_t)128*Kn, &Bsub[slot][4096 + w*512]); }while(0)

#define W_LG  asm volatile("s_waitcnt lgkmcnt(0)" ::: "memory")
#define W_VM8 asm volatile("s_waitcnt vmcnt(8) lgkmcnt(0)" ::: "memory")
#define W_VM4 asm volatile("s_waitcnt vmcnt(4) lgkmcnt(0)" ::: "memory")
#define W_VM0 asm volatile("s_waitcnt vmcnt(0) lgkmcnt(0)" ::: "memory")

#define PHASE(slot, nh, STG_STMT, WAIT) do{                                          \
        if (nh == 0){                                                                \
            _Pragma("unroll")                                                        \
            for (int m = 0; m < 8; m++)                                              \
                af[m] = *(const bf16x8*)(&Asub[slot][(wm*128 + m*16 + l16)*32 + swc]); \
        }                                                                            \
        _Pragma("unroll")                                                            \
        for (int nl = 0; nl < 2; nl++)                                               \
            bfr[nl] = *(const bf16x8*)(&Bsub[slot][(wn*64 + ((nh)*2+nl)*16 + l16)*32 + swc]); \
        STG_STMT;                                                                    \
        WAIT;                                                                        \
        __syncthreads();                                                             \
        __builtin_amdgcn_s_setprio(1);                                               \
        _Pragma("unroll")                                                            \
        for (int m = 0; m < 8; m++){                                                 \
            acc[m][(nh)*2+0] = __builtin_amdgcn_mfma_f32_16x16x32_bf16(af[m], bfr[0], acc[m][(nh)*2+0], 0,0,0); \
            acc[m][(nh)*2+1] = __builtin_amdgcn_mfma_f32_16x16x32_bf16(af[m], bfr[1], acc[m][(nh)*2+1], 0,0,0); \
        }                                                                            \
        __builtin_amdgcn_s_setprio(0);                                               \
    }while(0)

    // prologue: stage slabs 0,1,2 (k0 = 0,32,64) into slots 0,1,2 = 12 loads
    STGA(0, 0);  STGB(0, 0);
    STGA(1, 32); STGB(1, 32);
    STGA(2, 64); STGB(2, 64);
    asm volatile("s_waitcnt vmcnt(8)" ::: "memory");   // slab 0 resident
    __syncthreads();

    // main: 15 iterations x 2 k-tiles; iteration j consumes slabs 4j..4j+3 and stages
    // slabs 4j+3..4j+6 (one part per phase, 3-4 phases ahead of consumption)
    for (int j = 0; j < 15; j++){
        const int kb = 128*j;
        PHASE(0, 0, STGA(3, kb+96),  W_LG);
        PHASE(0, 1, STGB(3, kb+96),  W_VM8);
        PHASE(1, 0, STGA(0, kb+128), W_LG);
        PHASE(1, 1, STGB(0, kb+128), W_VM8);
        PHASE(2, 0, STGA(1, kb+160), W_LG);
        PHASE(2, 1, STGB(1, kb+160), W_VM8);
        PHASE(3, 0, STGA(2, kb+192), W_LG);
        PHASE(3, 1, STGB(2, kb+192), W_VM8);
    }
    // peeled last iteration (slabs 60..63; only slab 63 left to stage): drain 8->4->0
    PHASE(0, 0, STGA(3, 2016), W_LG);
    PHASE(0, 1, STGB(3, 2016), W_VM8);
    PHASE(1, 0, (void)0,       W_LG);
    PHASE(1, 1, (void)0,       W_VM4);
    PHASE(2, 0, (void)0,       W_LG);
    PHASE(2, 1, (void)0,       W_VM0);
    PHASE(3, 0, (void)0,       W_LG);
    PHASE(3, 1, (void)0,       W_LG);

#undef PHASE
#undef STGA
#undef STGB

    // ---------------- epilogue ----------------
#pragma unroll
    for (int n = 0; n < 4; n++){
        int col = n0 + wn*64 + n*16 + l16;
        float bv;
        if (EPI == 3) bv = (col < 2048) ? bias0[col] : (col < 2560) ? bias1[col-2048] : bias2[col-2560];
        else          bv = bias0[col];
#pragma unroll
        for (int m = 0; m < 8; m++){
#pragma unroll
            for (int r = 0; r < 4; r++){
                int row = m0 + wm*128 + m*16 + quad*4 + r;   // C/D: col=lane&15, row=quad*4+reg
                float v = acc[m][n][r] + bv;
                if (EPI == 3){
                    int b = row >> 11, s = row & (SEQ-1);
                    if (col < 2048){
                        int hh = col >> 6, d = col & 63;
                        ((u16*)out0)[(((size_t)b*NHEADS + hh)*SEQ + s)*DKH + d] = f2bf(v * QSCALE);
                    } else if (col < 2560){
                        int c = col - 2048, gg = c >> 6, d = c & 63;
                        ((u16*)out1)[(((size_t)b*NGRP + gg)*SEQ + s)*DKH + d] = f2bf(v);
                    } else {
                        int c = col - 2560, gg = c >> 6, d = c & 63;
                        int t = s & 31;   // flash PV k-slot permutation
                        int pos = (t < 16) ? (((t >> 2) << 3) | (t & 3))
                                           : ((((t & 15) >> 2) << 3) | 4 | (t & 3));
                        int sp = (s & ~31) | pos;
                        ((u16*)out2)[(((size_t)b*NGRP + gg)*DKH + d)*SEQ + sp] =
                            __builtin_bit_cast(u16, (_Float16)v);   // V in f16 for PV MFMA
                    }
                } else {
                    ((float*)out0)[(size_t)row * DMODEL + col] = v;
                }
            }
        }
    }
}

// ---------------- flash attention v8 (best measured: 79.9us, 0 conflicts) ----------
// Reverted from v9 (rows=64, 8 waves/CU: 83.3us -> low-occupancy corner ruled out).
// 4-wave blocks, Q-tile 128 (32 q-rows/wave), grid 1024 = 4 blocks/CU = 16 waves/CU,
// 4 independent barrier domains. Permuted V^T -> single conflict-free b128 PV read.
// QK^T transposed (A=K, B=Q, 16x16x32_bf16), P in registers, exp2-domain softmax
// without max-subtraction, K=32 PV via k-slot permutation.
__global__ __launch_bounds__(256, 4) void flash_kern(
    const u16* __restrict__ Qb, const u16* __restrict__ Kb,
    const u16* __restrict__ Vt, u16* __restrict__ Ob)
{
    __shared__ alignas(16) u16 Ks[2][64*64];
    __shared__ alignas(16) u16 Vs[2][64*64];
    const int tid = threadIdx.x, w = tid >> 6, lane = tid & 63;
    const int quad = lane >> 4, l16 = lane & 15;
    const int q0 = blockIdx.x * 128;
    const int h  = blockIdx.y, b = blockIdx.z, g = h >> 2;

    const u16* Qg = Qb + (((size_t)b*NHEADS + h)*SEQ + q0 + w*32) * DKH;
    const u16* Kg = Kb + ((size_t)b*NGRP + g) * SEQ * DKH;   // [s][d] bf16
    const u16* Vg = Vt + ((size_t)b*NGRP + g) * DKH * SEQ;   // [d][s'] f16 (permuted)

    // staging: wave w covers rows w*16..w*16+15; lane -> (row lr, chunk lc), XOR swizzle
    const int lr = lane >> 3, lc = lane & 7;
    const int sw = lc ^ lr;
    const u16* gk0 = Kg + (size_t)(w*16 + lr) * DKH + sw*8;   // + kt*64*DKH
    const u16* gv0 = Vg + (size_t)(w*16 + lr) * SEQ + sw*8;   // + kt*64

    bf16x8 aq[2][2];   // [ks][nt] Q B-frags, kt-invariant (32 q-rows/wave)
#pragma unroll
    for (int nt = 0; nt < 2; nt++)
#pragma unroll
        for (int ks = 0; ks < 2; ks++)
            aq[ks][nt] = *(const bf16x8*)(Qg + (nt*16 + l16)*DKH + ks*32 + quad*8);

    float lsum[2] = {};
    f32x4 oa[2][4] = {};   // [nt(q)][dt(d)]

#define STAGE(buf, kt) do{                                                        \
        gld_lds16(gk0 + (size_t)(kt)*64*DKH,           Ks[buf] + (w*16)*64);      \
        gld_lds16(gk0 + (size_t)(kt)*64*DKH + 8*DKH,   Ks[buf] + (w*16+8)*64);    \
        gld_lds16(gv0 + (size_t)(kt)*64,               Vs[buf] + (w*16)*64);      \
        gld_lds16(gv0 + (size_t)(kt)*64 + (size_t)8*SEQ, Vs[buf] + (w*16+8)*64);  \
    }while(0)

    // Per 32-kv pair p (tiles kc=2p, 2p+1): QK^T + exp for both 16-tiles, pack f16;
    // PV: A = concat(pe,po); B = ONE b128 V^T read (chunk (4p+quad)^(l16&7)) thanks to
    // the global-side k-slot permutation -> one K=32 MFMA, zero bank conflicts.
#define COMPUTE(buf) do{                                                              \
        _Pragma("unroll")                                                             \
        for (int p = 0; p < 2; p++){                                                  \
            f16x4 pe[2], po[2];                                                       \
            _Pragma("unroll")                                                         \
            for (int hf = 0; hf < 2; hf++){                                           \
                const int kc = p*2 + hf;                                              \
                bf16x8 bk0 = *(const bf16x8*)(Ks[buf] + (kc*16 + l16)*64              \
                                              + ((quad     ^ (l16&7)) * 8));          \
                bf16x8 bk1 = *(const bf16x8*)(Ks[buf] + (kc*16 + l16)*64              \
                                              + (((4+quad) ^ (l16&7)) * 8));          \
                _Pragma("unroll")                                                     \
                for (int nt = 0; nt < 2; nt++){                                       \
                    f32x4 sa = {};                                                    \
                    sa = __builtin_amdgcn_mfma_f32_16x16x32_bf16(bk0, aq[0][nt], sa,0,0,0);\
                    sa = __builtin_amdgcn_mfma_f32_16x16x32_bf16(bk1, aq[1][nt], sa,0,0,0);\
                    float e0 = __builtin_amdgcn_exp2f(sa[0]);                         \
                    float e1 = __builtin_amdgcn_exp2f(sa[1]);                         \
                    float e2 = __builtin_amdgcn_exp2f(sa[2]);                         \
                    float e3 = __builtin_amdgcn_exp2f(sa[3]);                         \
                    lsum[nt] += (e0 + e1) + (e2 + e3);                                \
                    uint2 pk = make_uint2(                                            \
                        __builtin_bit_cast(uint32_t, __builtin_amdgcn_cvt_pkrtz(e0, e1)), \
                        __builtin_bit_cast(uint32_t, __builtin_amdgcn_cvt_pkrtz(e2, e3)));\
                    (hf ? po : pe)[nt] = __builtin_bit_cast(f16x4, pk);               \
                }                                                                     \
            }                                                                         \
            f16x8 pa8[2];                                                             \
            _Pragma("unroll")                                                         \
            for (int nt = 0; nt < 2; nt++)                                            \
                pa8[nt] = __builtin_shufflevector(pe[nt], po[nt], 0,1,2,3,4,5,6,7);   \
            _Pragma("unroll")                                                         \
            for (int dt = 0; dt < 4; dt++){                                           \
                f16x8 bv8 = *(const f16x8*)(Vs[buf] + (dt*16 + l16)*64                \
                             + (((4*p + quad) ^ (l16&7)) * 8));                       \
                _Pragma("unroll")                                                     \
                for (int nt = 0; nt < 2; nt++)                                        \
                    oa[nt][dt] = __builtin_amdgcn_mfma_f32_16x16x32_f16(              \
                        pa8[nt], bv8, oa[nt][dt], 0, 0, 0);                           \
            }                                                                         \
        }                                                                             \
    }while(0)

    STAGE(0, 0);
    __syncthreads();

    for (int kt2 = 0; kt2 < SEQ/128; ++kt2){
        int kt = kt2 * 2;
        STAGE(1, kt + 1);
        COMPUTE(0);
        __syncthreads();
        if (kt2 < SEQ/128 - 1) STAGE(0, kt + 2);
        COMPUTE(1);
        __syncthreads();
    }

    // lsum lives at lane l16 for q = nt*16+l16; reduce across quads, invert
#pragma unroll
    for (int nt = 0; nt < 2; nt++){
        float s = lsum[nt];
        s += __shfl_xor(s, 16, 64);
        s += __shfl_xor(s, 32, 64);
        lsum[nt] = 1.0f / s;
    }

    // oa D-layout: d = dt*16 + l16, q = nt*16 + quad*4 + r; inv from lane quad*4+r
#pragma unroll
    for (int nt = 0; nt < 2; nt++)
#pragma unroll
        for (int r = 0; r < 4; r++){
            float inv = __shfl(lsum[nt], quad*4 + r, 64);
            int q = q0 + w*32 + nt*16 + quad*4 + r;
#pragma unroll
            for (int dt = 0; dt < 4; dt++)
                Ob[((size_t)b*SEQ + q)*DMODEL + h*DKH + dt*16 + l16] = f2bf(oa[nt][dt][r] * inv);
        }
#undef STAGE
#undef COMPUTE
}

// ---------------- launcher ----------------

extern "C" void kernel_launch(void* const* d_in, const int* in_sizes, int n_in,
                              void* d_out, int out_size, void* d_ws, size_t ws_size,
                              hipStream_t stream)
{
    const float* x  = (const float*)d_in[0];
    const float* Wq = (const float*)d_in[1];
    const float* bq = (const float*)d_in[2];
    const float* Wk = (const float*)d_in[3];
    const float* bk = (const float*)d_in[4];
    const float* Wv = (const float*)d_in[5];
    const float* bv = (const float*)d_in[6];
    const float* Wo = (const float*)d_in[7];
    const float* bo = (const float*)d_in[8];

    uint8_t* p = (uint8_t*)d_ws;
    u16* xb  = (u16*)p; p += (size_t)MTOT*DMODEL*2;
    u16* WqT = (u16*)p; p += (size_t)DMODEL*DMODEL*2;          // } contiguous: Bt for
    u16* WkT = (u16*)p; p += (size_t)(NGRP*DKH)*DMODEL*2;      // } fused QKV GEMM
    u16* WvT = (u16*)p; p += (size_t)(NGRP*DKH)*DMODEL*2;
    u16* WoT = (u16*)p; p += (size_t)DMODEL*DMODEL*2;
    u16* Qb  = (u16*)p; p += (size_t)BATCH*NHEADS*SEQ*DKH*2;
    u16* Kb  = (u16*)p; p += (size_t)BATCH*NGRP*SEQ*DKH*2;
    u16* Vtb = (u16*)p; p += (size_t)BATCH*NGRP*DKH*SEQ*2;     // f16 bits, s-permuted
    u16* Ob  = (u16*)p; p += (size_t)MTOT*DMODEL*2;

    cvt_x_kern<<<MTOT*DMODEL/1024, 256, 0, stream>>>(x, xb);
    cvt_wT_all<<<dim3(160, 64), 256, 0, stream>>>(Wq, Wk, Wv, Wo, WqT, WkT, WvT, WoT);

    gemm_nt8<3><<<dim3(MTOT/256, 3072/256), 512, 0, stream>>>(
        xb, WqT, bq, bk, bv, Qb, Kb, Vtb, DMODEL);

    flash_kern<<<dim3(SEQ/128, NHEADS, BATCH), 256, 0, stream>>>(Qb, Kb, Vtb, Ob);

    gemm_nt8<2><<<dim3(MTOT/256, DMODEL/256), 512, 0, stream>>>(
        Ob, WoT, bo, nullptr, nullptr, d_out, nullptr, nullptr, DMODEL);
}

// Round 6
// 349.163 us; speedup vs baseline: 1.0820x; 1.0820x over previous
//
#include <hip/hip_runtime.h>
#include <stdint.h>

#define DMODEL 2048
#define NHEADS 32
#define NGRP 8
#define DKH 64
#define BATCH 2
#define SEQ 2048
#define MTOT (BATCH*SEQ)   // 4096

typedef unsigned short u16;
typedef __bf16 bf16x8 __attribute__((ext_vector_type(8)));
typedef float f32x4 __attribute__((ext_vector_type(4)));
typedef _Float16 f16x4 __attribute__((ext_vector_type(4)));
typedef _Float16 f16x8 __attribute__((ext_vector_type(8)));

#define QSCALE 0.18033688011112042f   // (1/8) * log2(e): softmax in exp2 domain

__device__ __forceinline__ u16 f2bf(float f){
    uint32_t x = __float_as_uint(f);
    x += 0x7FFFu + ((x >> 16) & 1u);   // RNE; inputs are finite
    return (u16)(x >> 16);
}

__device__ __forceinline__ void gld_lds16(const u16* g, u16* l){
    __builtin_amdgcn_global_load_lds(
        (const __attribute__((address_space(1))) uint32_t*)g,
        (__attribute__((address_space(3))) uint32_t*)l, 16, 0, 0);
}

// ---------------- conversion kernels ----------------

__global__ void cvt_x_kern(const float* __restrict__ x, u16* __restrict__ xb){
    int i = (blockIdx.x * 256 + threadIdx.x) * 4;
    float4 v = *(const float4*)(x + i);
    uint32_t lo = (uint32_t)f2bf(v.x) | ((uint32_t)f2bf(v.y) << 16);
    uint32_t hi = (uint32_t)f2bf(v.z) | ((uint32_t)f2bf(v.w) << 16);
    *(uint2*)(xb + i) = make_uint2(lo, hi);
}

// all 4 weights [K=2048][N] fp32 -> WT [N][K] bf16, fused into one launch
__global__ void cvt_wT_all(const float* __restrict__ Wq, const float* __restrict__ Wk,
                           const float* __restrict__ Wv, const float* __restrict__ Wo,
                           u16* __restrict__ WqT, u16* __restrict__ WkT,
                           u16* __restrict__ WvT, u16* __restrict__ WoT){
    __shared__ float t[32][33];
    int bx = blockIdx.x;
    const float* W; u16* T; int N; int cx;
    if (bx < 64)      { W = Wq; T = WqT; N = 2048; cx = bx; }
    else if (bx < 80) { W = Wk; T = WkT; N = 512;  cx = bx - 64; }
    else if (bx < 96) { W = Wv; T = WvT; N = 512;  cx = bx - 80; }
    else              { W = Wo; T = WoT; N = 2048; cx = bx - 96; }
    int tx = threadIdx.x & 31, ty = threadIdx.x >> 5;
    int n0 = cx * 32, k0 = blockIdx.y * 32;
#pragma unroll
    for (int i = 0; i < 4; i++)
        t[ty*4+i][tx] = W[(size_t)(k0 + ty*4 + i) * N + n0 + tx];
    __syncthreads();
#pragma unroll
    for (int i = 0; i < 4; i++)
        T[(size_t)(n0 + ty*4 + i) * DMODEL + k0 + tx] = f2bf(t[tx][ty*4+i]);
}

// ---------------- 8-phase 256x256 NT GEMM (guide T2+T3+T4+T5 template) --------------
// R5 post-mortem: the schedule was correct but __syncthreads() emits an implicit
// "s_waitcnt vmcnt(0) lgkmcnt(0)" before s_barrier (guide §5, m97 asm) -- it drained the
// ENTIRE staging queue every phase, destroying the counted-vmcnt pipeline (MfmaUtil 18%,
// VALU 9%, ~2000 cyc/phase). Fix: raw __builtin_amdgcn_s_barrier() (what m201 uses).
// Correctness with raw barriers:
//  - lgkmcnt(0) BEFORE each barrier => every wave's ds_reads of a slot are drained
//    before any wave can overwrite that slot after the barrier (overwrite of slot s is
//    issued 1+ phases after s's last read phase).
//  - per-wave vmcnt ledger: 2 loads/phase, W_VM8 at odd phases retires exactly the
//    4 loads of the slab consumed 3 phases later (slab in slot s, iter j, is staged
//    6 phases ahead, confirmed at distance 3). Peel drains 8->4->0.
// LDS swizzle: chunk(16B) ^= (row>>1)&3 on the GLOBAL source + on ds_read addr
// (staging dest stays linear for global_load_lds, m173/m104): b128 reads max 2-way = free.
// EPI 3: fused QKV epilogue (Q*QSCALE bf16 [b][h][s][d]; K bf16 [b][g][s][d];
//        V^T f16 [b][g][d][s'] with the flash PV k-slot permutation in s').
// EPI 2: fp32 row-major + bias.
template<int EPI>
__global__ __launch_bounds__(512, 2) void gemm_nt8(
    const u16* __restrict__ A, const u16* __restrict__ Bt,
    const float* __restrict__ bias0, const float* __restrict__ bias1, const float* __restrict__ bias2,
    void* __restrict__ out0, void* __restrict__ out1, void* __restrict__ out2, int Kn)
{
    __shared__ alignas(16) u16 Asub[4][8192];   // 4 slots x 256 rows x 32 elems = 64 KiB
    __shared__ alignas(16) u16 Bsub[4][8192];   // 64 KiB
    const int tid = threadIdx.x, w = tid >> 6, lane = tid & 63;
    const int quad = lane >> 4, l16 = lane & 15;
    const int wm = w >> 2, wn = w & 3;

    // T1: XCD-bijective chunked swizzle on the flattened block id (nwg % 8 == 0 here)
    int bid = blockIdx.y * gridDim.x + blockIdx.x;
    int nwg = gridDim.x * gridDim.y;
    int cpx = nwg >> 3;
    int sbid = (bid & 7) * cpx + (bid >> 3);
    int bx = sbid % gridDim.x, by = sbid / gridDim.x;
    const int m0 = bx * 256, n0 = by * 256;

    // staging thread map: row = i*128 + w*16 + (lane>>2), 16B chunk c = lane&3
    const int srow = w*16 + (lane >> 2);
    const int sc   = lane & 3;
    const int gc   = sc ^ ((srow >> 1) & 3);        // inverse read-swizzle on global src
    const u16* gA = A  + (size_t)(m0 + srow) * Kn + gc*8;
    const u16* gB = Bt + (size_t)(n0 + srow) * Kn + gc*8;

    // frag-read swizzled chunk (row = 16*X + l16 -> (row>>1)&3 == (l16>>1)&3)
    const int swc = (quad ^ ((l16 >> 1) & 3)) * 8;

    bf16x8 af[8], bfr[2];
    f32x4 acc[8][4] = {};

#define STGA(slot, kk) do{ \
        gld_lds16(gA + (kk),                  &Asub[slot][w*512]); \
        gld_lds16(gA + (kk) + (size_t)128*Kn, &Asub[slot][4096 + w*512]); }while(0)
#define STGB(slot, kk) do{ \
        gld_lds16(gB + (kk),                  &Bsub[slot][w*512]); \
        gld_lds16(gB + (kk) + (size_t)128*Kn, &Bsub[slot][4096 + w*512]); }while(0)

#define W_LG  asm volatile("s_waitcnt lgkmcnt(0)" ::: "memory")
#define W_VM8 asm volatile("s_waitcnt vmcnt(8) lgkmcnt(0)" ::: "memory")
#define W_VM4 asm volatile("s_waitcnt vmcnt(4) lgkmcnt(0)" ::: "memory")
#define W_VM0 asm volatile("s_waitcnt vmcnt(0) lgkmcnt(0)" ::: "memory")

#define PHASE(slot, nh, STG_STMT, WAIT) do{                                          \
        if (nh == 0){                                                                \
            _Pragma("unroll")                                                        \
            for (int m = 0; m < 8; m++)                                              \
                af[m] = *(const bf16x8*)(&Asub[slot][(wm*128 + m*16 + l16)*32 + swc]); \
        }                                                                            \
        _Pragma("unroll")                                                            \
        for (int nl = 0; nl < 2; nl++)                                               \
            bfr[nl] = *(const bf16x8*)(&Bsub[slot][(wn*64 + ((nh)*2+nl)*16 + l16)*32 + swc]); \
        STG_STMT;                                                                    \
        WAIT;                                                                        \
        __builtin_amdgcn_s_barrier();                                                \
        __builtin_amdgcn_s_setprio(1);                                               \
        _Pragma("unroll")                                                            \
        for (int m = 0; m < 8; m++){                                                 \
            acc[m][(nh)*2+0] = __builtin_amdgcn_mfma_f32_16x16x32_bf16(af[m], bfr[0], acc[m][(nh)*2+0], 0,0,0); \
            acc[m][(nh)*2+1] = __builtin_amdgcn_mfma_f32_16x16x32_bf16(af[m], bfr[1], acc[m][(nh)*2+1], 0,0,0); \
        }                                                                            \
        __builtin_amdgcn_s_setprio(0);                                               \
    }while(0)

    // prologue: stage slabs 0,1,2 (k0 = 0,32,64) into slots 0,1,2 = 12 loads
    STGA(0, 0);  STGB(0, 0);
    STGA(1, 32); STGB(1, 32);
    STGA(2, 64); STGB(2, 64);
    asm volatile("s_waitcnt vmcnt(8)" ::: "memory");   // slab 0 resident
    __builtin_amdgcn_s_barrier();

    // main: 15 iterations x 4 slabs; iteration j consumes slabs 4j..4j+3 and stages
    // slabs 4j+3..4j+6 (one 128-row part per phase, 3-6 phases ahead of consumption)
    for (int j = 0; j < 15; j++){
        const int kb = 128*j;
        PHASE(0, 0, STGA(3, kb+96),  W_LG);
        PHASE(0, 1, STGB(3, kb+96),  W_VM8);
        PHASE(1, 0, STGA(0, kb+128), W_LG);
        PHASE(1, 1, STGB(0, kb+128), W_VM8);
        PHASE(2, 0, STGA(1, kb+160), W_LG);
        PHASE(2, 1, STGB(1, kb+160), W_VM8);
        PHASE(3, 0, STGA(2, kb+192), W_LG);
        PHASE(3, 1, STGB(2, kb+192), W_VM8);
    }
    // peeled last iteration (slabs 60..63; only slab 63 left to stage): drain 8->4->0
    PHASE(0, 0, STGA(3, 2016), W_LG);
    PHASE(0, 1, STGB(3, 2016), W_VM8);
    PHASE(1, 0, (void)0,       W_LG);
    PHASE(1, 1, (void)0,       W_VM4);
    PHASE(2, 0, (void)0,       W_LG);
    PHASE(2, 1, (void)0,       W_VM0);
    PHASE(3, 0, (void)0,       W_LG);
    PHASE(3, 1, (void)0,       W_LG);

#undef PHASE
#undef STGA
#undef STGB

    // ---------------- epilogue ----------------
#pragma unroll
    for (int n = 0; n < 4; n++){
        int col = n0 + wn*64 + n*16 + l16;
        float bv;
        if (EPI == 3) bv = (col < 2048) ? bias0[col] : (col < 2560) ? bias1[col-2048] : bias2[col-2560];
        else          bv = bias0[col];
#pragma unroll
        for (int m = 0; m < 8; m++){
#pragma unroll
            for (int r = 0; r < 4; r++){
                int row = m0 + wm*128 + m*16 + quad*4 + r;   // C/D: col=lane&15, row=quad*4+reg
                float v = acc[m][n][r] + bv;
                if (EPI == 3){
                    int b = row >> 11, s = row & (SEQ-1);
                    if (col < 2048){
                        int hh = col >> 6, d = col & 63;
                        ((u16*)out0)[(((size_t)b*NHEADS + hh)*SEQ + s)*DKH + d] = f2bf(v * QSCALE);
                    } else if (col < 2560){
                        int c = col - 2048, gg = c >> 6, d = c & 63;
                        ((u16*)out1)[(((size_t)b*NGRP + gg)*SEQ + s)*DKH + d] = f2bf(v);
                    } else {
                        int c = col - 2560, gg = c >> 6, d = c & 63;
                        int t = s & 31;   // flash PV k-slot permutation
                        int pos = (t < 16) ? (((t >> 2) << 3) | (t & 3))
                                           : ((((t & 15) >> 2) << 3) | 4 | (t & 3));
                        int sp = (s & ~31) | pos;
                        ((u16*)out2)[(((size_t)b*NGRP + gg)*DKH + d)*SEQ + sp] =
                            __builtin_bit_cast(u16, (_Float16)v);   // V in f16 for PV MFMA
                    }
                } else {
                    ((float*)out0)[(size_t)row * DMODEL + col] = v;
                }
            }
        }
    }
}

// ---------------- flash attention v8 (best measured: 79.9us, 0 conflicts) ----------
// 4-wave blocks, Q-tile 128 (32 q-rows/wave), grid 1024 = 4 blocks/CU = 16 waves/CU,
// 4 independent barrier domains. Permuted V^T -> single conflict-free b128 PV read.
// QK^T transposed (A=K, B=Q, 16x16x32_bf16), P in registers, exp2-domain softmax
// without max-subtraction, K=32 PV via k-slot permutation.
// NOTE: __syncthreads() here is INTENTIONAL -- its implicit vmcnt(0) drain IS the
// synchronization that makes the freshly-staged dbuf half readable.
__global__ __launch_bounds__(256, 4) void flash_kern(
    const u16* __restrict__ Qb, const u16* __restrict__ Kb,
    const u16* __restrict__ Vt, u16* __restrict__ Ob)
{
    __shared__ alignas(16) u16 Ks[2][64*64];
    __shared__ alignas(16) u16 Vs[2][64*64];
    const int tid = threadIdx.x, w = tid >> 6, lane = tid & 63;
    const int quad = lane >> 4, l16 = lane & 15;
    const int q0 = blockIdx.x * 128;
    const int h  = blockIdx.y, b = blockIdx.z, g = h >> 2;

    const u16* Qg = Qb + (((size_t)b*NHEADS + h)*SEQ + q0 + w*32) * DKH;
    const u16* Kg = Kb + ((size_t)b*NGRP + g) * SEQ * DKH;   // [s][d] bf16
    const u16* Vg = Vt + ((size_t)b*NGRP + g) * DKH * SEQ;   // [d][s'] f16 (permuted)

    // staging: wave w covers rows w*16..w*16+15; lane -> (row lr, chunk lc), XOR swizzle
    const int lr = lane >> 3, lc = lane & 7;
    const int sw = lc ^ lr;
    const u16* gk0 = Kg + (size_t)(w*16 + lr) * DKH + sw*8;   // + kt*64*DKH
    const u16* gv0 = Vg + (size_t)(w*16 + lr) * SEQ + sw*8;   // + kt*64

    bf16x8 aq[2][2];   // [ks][nt] Q B-frags, kt-invariant (32 q-rows/wave)
#pragma unroll
    for (int nt = 0; nt < 2; nt++)
#pragma unroll
        for (int ks = 0; ks < 2; ks++)
            aq[ks][nt] = *(const bf16x8*)(Qg + (nt*16 + l16)*DKH + ks*32 + quad*8);

    float lsum[2] = {};
    f32x4 oa[2][4] = {};   // [nt(q)][dt(d)]

#define STAGE(buf, kt) do{                                                        \
        gld_lds16(gk0 + (size_t)(kt)*64*DKH,           Ks[buf] + (w*16)*64);      \
        gld_lds16(gk0 + (size_t)(kt)*64*DKH + 8*DKH,   Ks[buf] + (w*16+8)*64);    \
        gld_lds16(gv0 + (size_t)(kt)*64,               Vs[buf] + (w*16)*64);      \
        gld_lds16(gv0 + (size_t)(kt)*64 + (size_t)8*SEQ, Vs[buf] + (w*16+8)*64);  \
    }while(0)

    // Per 32-kv pair p (tiles kc=2p, 2p+1): QK^T + exp for both 16-tiles, pack f16;
    // PV: A = concat(pe,po); B = ONE b128 V^T read (chunk (4p+quad)^(l16&7)) thanks to
    // the global-side k-slot permutation -> one K=32 MFMA, zero bank conflicts.
#define COMPUTE(buf) do{                                                              \
        _Pragma("unroll")                                                             \
        for (int p = 0; p < 2; p++){                                                  \
            f16x4 pe[2], po[2];                                                       \
            _Pragma("unroll")                                                         \
            for (int hf = 0; hf < 2; hf++){                                           \
                const int kc = p*2 + hf;                                              \
                bf16x8 bk0 = *(const bf16x8*)(Ks[buf] + (kc*16 + l16)*64              \
                                              + ((quad     ^ (l16&7)) * 8));          \
                bf16x8 bk1 = *(const bf16x8*)(Ks[buf] + (kc*16 + l16)*64              \
                                              + (((4+quad) ^ (l16&7)) * 8));          \
                _Pragma("unroll")                                                     \
                for (int nt = 0; nt < 2; nt++){                                       \
                    f32x4 sa = {};                                                    \
                    sa = __builtin_amdgcn_mfma_f32_16x16x32_bf16(bk0, aq[0][nt], sa,0,0,0);\
                    sa = __builtin_amdgcn_mfma_f32_16x16x32_bf16(bk1, aq[1][nt], sa,0,0,0);\
                    float e0 = __builtin_amdgcn_exp2f(sa[0]);                         \
                    float e1 = __builtin_amdgcn_exp2f(sa[1]);                         \
                    float e2 = __builtin_amdgcn_exp2f(sa[2]);                         \
                    float e3 = __builtin_amdgcn_exp2f(sa[3]);                         \
                    lsum[nt] += (e0 + e1) + (e2 + e3);                                \
                    uint2 pk = make_uint2(                                            \
                        __builtin_bit_cast(uint32_t, __builtin_amdgcn_cvt_pkrtz(e0, e1)), \
                        __builtin_bit_cast(uint32_t, __builtin_amdgcn_cvt_pkrtz(e2, e3)));\
                    (hf ? po : pe)[nt] = __builtin_bit_cast(f16x4, pk);               \
                }                                                                     \
            }                                                                         \
            f16x8 pa8[2];                                                             \
            _Pragma("unroll")                                                         \
            for (int nt = 0; nt < 2; nt++)                                            \
                pa8[nt] = __builtin_shufflevector(pe[nt], po[nt], 0,1,2,3,4,5,6,7);   \
            _Pragma("unroll")                                                         \
            for (int dt = 0; dt < 4; dt++){                                           \
                f16x8 bv8 = *(const f16x8*)(Vs[buf] + (dt*16 + l16)*64                \
                             + (((4*p + quad) ^ (l16&7)) * 8));                       \
                _Pragma("unroll")                                                     \
                for (int nt = 0; nt < 2; nt++)                                        \
                    oa[nt][dt] = __builtin_amdgcn_mfma_f32_16x16x32_f16(              \
                        pa8[nt], bv8, oa[nt][dt], 0, 0, 0);                           \
            }                                                                         \
        }                                                                             \
    }while(0)

    STAGE(0, 0);
    __syncthreads();

    for (int kt2 = 0; kt2 < SEQ/128; ++kt2){
        int kt = kt2 * 2;
        STAGE(1, kt + 1);
        COMPUTE(0);
        __syncthreads();
        if (kt2 < SEQ/128 - 1) STAGE(0, kt + 2);
        COMPUTE(1);
        __syncthreads();
    }

    // lsum lives at lane l16 for q = nt*16+l16; reduce across quads, invert
#pragma unroll
    for (int nt = 0; nt < 2; nt++){
        float s = lsum[nt];
        s += __shfl_xor(s, 16, 64);
        s += __shfl_xor(s, 32, 64);
        lsum[nt] = 1.0f / s;
    }

    // oa D-layout: d = dt*16 + l16, q = nt*16 + quad*4 + r; inv from lane quad*4+r
#pragma unroll
    for (int nt = 0; nt < 2; nt++)
#pragma unroll
        for (int r = 0; r < 4; r++){
            float inv = __shfl(lsum[nt], quad*4 + r, 64);
            int q = q0 + w*32 + nt*16 + quad*4 + r;
#pragma unroll
            for (int dt = 0; dt < 4; dt++)
                Ob[((size_t)b*SEQ + q)*DMODEL + h*DKH + dt*16 + l16] = f2bf(oa[nt][dt][r] * inv);
        }
#undef STAGE
#undef COMPUTE
}

// ---------------- launcher ----------------

extern "C" void kernel_launch(void* const* d_in, const int* in_sizes, int n_in,
                              void* d_out, int out_size, void* d_ws, size_t ws_size,
                              hipStream_t stream)
{
    const float* x  = (const float*)d_in[0];
    const float* Wq = (const float*)d_in[1];
    const float* bq = (const float*)d_in[2];
    const float* Wk = (const float*)d_in[3];
    const float* bk = (const float*)d_in[4];
    const float* Wv = (const float*)d_in[5];
    const float* bv = (const float*)d_in[6];
    const float* Wo = (const float*)d_in[7];
    const float* bo = (const float*)d_in[8];

    uint8_t* p = (uint8_t*)d_ws;
    u16* xb  = (u16*)p; p += (size_t)MTOT*DMODEL*2;
    u16* WqT = (u16*)p; p += (size_t)DMODEL*DMODEL*2;          // } contiguous: Bt for
    u16* WkT = (u16*)p; p += (size_t)(NGRP*DKH)*DMODEL*2;      // } fused QKV GEMM
    u16* WvT = (u16*)p; p += (size_t)(NGRP*DKH)*DMODEL*2;
    u16* WoT = (u16*)p; p += (size_t)DMODEL*DMODEL*2;
    u16* Qb  = (u16*)p; p += (size_t)BATCH*NHEADS*SEQ*DKH*2;
    u16* Kb  = (u16*)p; p += (size_t)BATCH*NGRP*SEQ*DKH*2;
    u16* Vtb = (u16*)p; p += (size_t)BATCH*NGRP*DKH*SEQ*2;     // f16 bits, s-permuted
    u16* Ob  = (u16*)p; p += (size_t)MTOT*DMODEL*2;

    cvt_x_kern<<<MTOT*DMODEL/1024, 256, 0, stream>>>(x, xb);
    cvt_wT_all<<<dim3(160, 64), 256, 0, stream>>>(Wq, Wk, Wv, Wo, WqT, WkT, WvT, WoT);

    gemm_nt8<3><<<dim3(MTOT/256, 3072/256), 512, 0, stream>>>(
        xb, WqT, bq, bk, bv, Qb, Kb, Vtb, DMODEL);

    flash_kern<<<dim3(SEQ/128, NHEADS, BATCH), 256, 0, stream>>>(Qb, Kb, Vtb, Ob);

    gemm_nt8<2><<<dim3(MTOT/256, DMODEL/256), 512, 0, stream>>>(
        Ob, WoT, bo, nullptr, nullptr, d_out, nullptr, nullptr, DMODEL);
}

// Round 7
// 330.597 us; speedup vs baseline: 1.1427x; 1.0562x over previous
//
#include <hip/hip_runtime.h>
#include <stdint.h>

#define DMODEL 2048
#define NHEADS 32
#define NGRP 8
#define DKH 64
#define BATCH 2
#define SEQ 2048
#define MTOT (BATCH*SEQ)   // 4096

typedef unsigned short u16;
typedef __bf16 bf16x8 __attribute__((ext_vector_type(8)));
typedef float f32x4 __attribute__((ext_vector_type(4)));
typedef _Float16 f16x4 __attribute__((ext_vector_type(4)));
typedef _Float16 f16x8 __attribute__((ext_vector_type(8)));

#define QSCALE 0.18033688011112042f   // (1/8) * log2(e): softmax in exp2 domain

__device__ __forceinline__ u16 f2bf(float f){
    uint32_t x = __float_as_uint(f);
    x += 0x7FFFu + ((x >> 16) & 1u);   // RNE; inputs are finite
    return (u16)(x >> 16);
}

__device__ __forceinline__ void gld_lds16(const u16* g, u16* l){
    __builtin_amdgcn_global_load_lds(
        (const __attribute__((address_space(1))) uint32_t*)g,
        (__attribute__((address_space(3))) uint32_t*)l, 16, 0, 0);
}

// ---------------- conversion kernels ----------------

__global__ void cvt_x_kern(const float* __restrict__ x, u16* __restrict__ xb){
    int i = (blockIdx.x * 256 + threadIdx.x) * 4;
    float4 v = *(const float4*)(x + i);
    uint32_t lo = (uint32_t)f2bf(v.x) | ((uint32_t)f2bf(v.y) << 16);
    uint32_t hi = (uint32_t)f2bf(v.z) | ((uint32_t)f2bf(v.w) << 16);
    *(uint2*)(xb + i) = make_uint2(lo, hi);
}

// all 4 weights [K=2048][N] fp32 -> WT [N][K] bf16, fused into one launch
__global__ void cvt_wT_all(const float* __restrict__ Wq, const float* __restrict__ Wk,
                           const float* __restrict__ Wv, const float* __restrict__ Wo,
                           u16* __restrict__ WqT, u16* __restrict__ WkT,
                           u16* __restrict__ WvT, u16* __restrict__ WoT){
    __shared__ float t[32][33];
    int bx = blockIdx.x;
    const float* W; u16* T; int N; int cx;
    if (bx < 64)      { W = Wq; T = WqT; N = 2048; cx = bx; }
    else if (bx < 80) { W = Wk; T = WkT; N = 512;  cx = bx - 64; }
    else if (bx < 96) { W = Wv; T = WvT; N = 512;  cx = bx - 80; }
    else              { W = Wo; T = WoT; N = 2048; cx = bx - 96; }
    int tx = threadIdx.x & 31, ty = threadIdx.x >> 5;
    int n0 = cx * 32, k0 = blockIdx.y * 32;
#pragma unroll
    for (int i = 0; i < 4; i++)
        t[ty*4+i][tx] = W[(size_t)(k0 + ty*4 + i) * N + n0 + tx];
    __syncthreads();
#pragma unroll
    for (int i = 0; i < 4; i++)
        T[(size_t)(n0 + ty*4 + i) * DMODEL + k0 + tx] = f2bf(t[tx][ty*4+i]);
}

// ---------------- v3: faithful m201-style 8-phase 256x256 NT GEMM (QKV only) ---------
// R6 post-mortem: my variant deviated from the verified template in (1) lgkm-before-
// barrier (serial drain), (2) one barrier/phase, (3) per-2-phase vmcnt. This port is
// faithful: BK=64; 2 buffers x 2 kk-halves; per phase {ds_read frags; 2 gld_lds;
// [vmcnt(4) at ph4/ph8 only]; s_barrier; lgkmcnt(0); sched_barrier(0) (rule #18);
// setprio(1); 16 MFMA; setprio(0); s_barrier}.
// LDS: A/B each [2 buf][2 kk][256 rows][4 chunks x 16B] = 128 KiB. Chunk XOR
// swizzle ^= ((row>>1)&3): read b128 spans 8 distinct bank-groups over 8 rows = 2-way
// max = free. Staging dest linear (global source pre-swizzled, m173/m104).
// Ledger (verified): iter j computes tiles a=2j (buf0), b=2j+1 (buf1);
//   ph1 SA(1,1,b) ph2 SB(1,1,b) ph3 SA(0,0,c) ph4 SB(0,0,c)+VM4
//   ph5 SA(0,1,c) ph6 SB(0,1,c) ph7 SA(1,0,d) ph8 SB(1,0,d)+VM4   (c=2j+2, d=2j+3)
// Each read phase's source was staged 5-6 phases earlier and confirmed by the VM4
// (2 loads/phase; vmcnt(4) leaves only the newest 2 phases unconfirmed). WAR: a
// half's last ds_read is confirmed by that phase's lgkm(0), ordered before any
// overwrite-issue by the phase-end barrier. Tail: staged tile index clamped to 31
// (harmless re-stage keeps the wait ledger exact). K hardcoded 2048 (32 tiles).
template<int EPI>
__global__ __launch_bounds__(512, 2) void gemm_nt8(
    const u16* __restrict__ A, const u16* __restrict__ Bt,
    const float* __restrict__ bias0, const float* __restrict__ bias1, const float* __restrict__ bias2,
    void* __restrict__ out0, void* __restrict__ out1, void* __restrict__ out2, int Kn)
{
    __shared__ alignas(16) u16 Asub[2][2][8192];   // [buf][kk][256 rows x 4 chunks x 8] = 64 KiB
    __shared__ alignas(16) u16 Bsub[2][2][8192];   // 64 KiB
    const int tid = threadIdx.x, w = tid >> 6, lane = tid & 63;
    const int quad = lane >> 4, l16 = lane & 15;
    const int wm = w >> 2, wn = w & 3;

    // T1: XCD-bijective chunked swizzle (nwg % 8 == 0 for both grids used)
    int bid = blockIdx.y * gridDim.x + blockIdx.x;
    int nwg = gridDim.x * gridDim.y;
    int cpx = nwg >> 3;
    int sbid = (bid & 7) * cpx + (bid >> 3);
    int bx = sbid % gridDim.x, by = sbid / gridDim.x;
    const int m0 = bx * 256, n0 = by * 256;

    // staging: wave w, call c in {0,1}: rows w*32 + c*16 + (lane>>2), LDS chunk lane&3,
    // global chunk (lane&3) ^ ((lane>>3)&3)  [= (row>>1)&3 key, row-part divisible by 4]
    const u16* gAw = A  + (size_t)(m0 + w*32 + (lane >> 2)) * Kn + (((lane&3) ^ ((lane>>3)&3)) * 8);
    const u16* gBw = Bt + (size_t)(n0 + w*32 + (lane >> 2)) * Kn + (((lane&3) ^ ((lane>>3)&3)) * 8);

    const int swc = (quad ^ ((l16 >> 1) & 3)) * 8;   // read-side swizzled chunk (u16 units)

    bf16x8 af[8], bfr[2];
    f32x4 acc[8][4] = {};

#define SA(buf, kk, kt) do{ \
        gld_lds16(gAw + (kt)*64 + (kk)*32,                   &Asub[buf][kk][w*1024]);       \
        gld_lds16(gAw + (size_t)16*Kn + (kt)*64 + (kk)*32,   &Asub[buf][kk][w*1024 + 512]); \
    }while(0)
#define SB(buf, kk, kt) do{ \
        gld_lds16(gBw + (kt)*64 + (kk)*32,                   &Bsub[buf][kk][w*1024]);       \
        gld_lds16(gBw + (size_t)16*Kn + (kt)*64 + (kk)*32,   &Bsub[buf][kk][w*1024 + 512]); \
    }while(0)

#define NW  ((void)0)
#define VM4 asm volatile("s_waitcnt vmcnt(4)" ::: "memory")

#define PH(buf, np, kk, STG, WAIT) do{                                               \
        if (np == 0){                                                                \
            _Pragma("unroll")                                                        \
            for (int m = 0; m < 8; m++)                                              \
                af[m] = *(const bf16x8*)(&Asub[buf][kk][(wm*128 + m*16 + l16)*32 + swc]); \
        }                                                                            \
        _Pragma("unroll")                                                            \
        for (int nl = 0; nl < 2; nl++)                                               \
            bfr[nl] = *(const bf16x8*)(&Bsub[buf][kk][(wn*64 + ((np)*2+nl)*16 + l16)*32 + swc]); \
        STG;                                                                         \
        WAIT;                                                                        \
        __builtin_amdgcn_s_barrier();                                                \
        asm volatile("s_waitcnt lgkmcnt(0)" ::: "memory");                           \
        __builtin_amdgcn_sched_barrier(0);                                           \
        __builtin_amdgcn_s_setprio(1);                                               \
        _Pragma("unroll")                                                            \
        for (int m = 0; m < 8; m++){                                                 \
            acc[m][(np)*2+0] = __builtin_amdgcn_mfma_f32_16x16x32_bf16(af[m], bfr[0], acc[m][(np)*2+0], 0,0,0); \
            acc[m][(np)*2+1] = __builtin_amdgcn_mfma_f32_16x16x32_bf16(af[m], bfr[1], acc[m][(np)*2+1], 0,0,0); \
        }                                                                            \
        __builtin_amdgcn_s_setprio(0);                                               \
        __builtin_amdgcn_s_barrier();                                                \
    }while(0)

    // prologue: tile0 (all 4 halves) + tile1 kk0 = 12 loads/wave; confirm tile0 (vmcnt 4)
    SA(0, 0, 0); SB(0, 0, 0);
    SA(0, 1, 0); SB(0, 1, 0);
    SA(1, 0, 1); SB(1, 0, 1);
    asm volatile("s_waitcnt vmcnt(4)" ::: "memory");
    __builtin_amdgcn_s_barrier();

    for (int j = 0; j < 16; j++){
        const int tb = 2*j + 1;
        const int tc = (2*j + 2 < 32) ? 2*j + 2 : 31;
        const int td = (2*j + 3 < 32) ? 2*j + 3 : 31;
        PH(0, 0, 0, SA(1, 1, tb), NW);
        PH(0, 1, 0, SB(1, 1, tb), NW);
        PH(0, 0, 1, SA(0, 0, tc), NW);
        PH(0, 1, 1, SB(0, 0, tc), VM4);
        PH(1, 0, 0, SA(0, 1, tc), NW);
        PH(1, 1, 0, SB(0, 1, tc), NW);
        PH(1, 0, 1, SA(1, 0, td), NW);
        PH(1, 1, 1, SB(1, 0, td), VM4);
    }

#undef PH
#undef SA
#undef SB
#undef NW
#undef VM4

    // ---------------- epilogue ----------------
#pragma unroll
    for (int n = 0; n < 4; n++){
        int col = n0 + wn*64 + n*16 + l16;
        float bv;
        if (EPI == 3) bv = (col < 2048) ? bias0[col] : (col < 2560) ? bias1[col-2048] : bias2[col-2560];
        else          bv = bias0[col];
#pragma unroll
        for (int m = 0; m < 8; m++){
#pragma unroll
            for (int r = 0; r < 4; r++){
                int row = m0 + wm*128 + m*16 + quad*4 + r;   // C/D: col=lane&15, row=quad*4+reg
                float v = acc[m][n][r] + bv;
                if (EPI == 3){
                    int b = row >> 11, s = row & (SEQ-1);
                    if (col < 2048){
                        int hh = col >> 6, d = col & 63;
                        ((u16*)out0)[(((size_t)b*NHEADS + hh)*SEQ + s)*DKH + d] = f2bf(v * QSCALE);
                    } else if (col < 2560){
                        int c = col - 2048, gg = c >> 6, d = c & 63;
                        ((u16*)out1)[(((size_t)b*NGRP + gg)*SEQ + s)*DKH + d] = f2bf(v);
                    } else {
                        int c = col - 2560, gg = c >> 6, d = c & 63;
                        int t = s & 31;   // flash PV k-slot permutation
                        int pos = (t < 16) ? (((t >> 2) << 3) | (t & 3))
                                           : ((((t & 15) >> 2) << 3) | 4 | (t & 3));
                        int sp = (s & ~31) | pos;
                        ((u16*)out2)[(((size_t)b*NGRP + gg)*DKH + d)*SEQ + sp] =
                            __builtin_bit_cast(u16, (_Float16)v);   // V in f16 for PV MFMA
                    }
                } else {
                    ((float*)out0)[(size_t)row * DMODEL + col] = v;
                }
            }
        }
    }
}

// ---------------- m97-style 128x128 NT GEMM (restored, verified; O-proj) ------------
// C = A[M][K] * Bt[N][K]^T + bias. EPI 2: fp32 row-major + bias.
template<int EPI>
__global__ __launch_bounds__(256, 2) void gemm_nt(
    const u16* __restrict__ A, const u16* __restrict__ Bt,
    const float* __restrict__ bias0, const float* __restrict__ bias1, const float* __restrict__ bias2,
    void* __restrict__ out0, void* __restrict__ out1, void* __restrict__ out2, int Kn)
{
    __shared__ alignas(16) u16 As[128*32];
    __shared__ alignas(16) u16 Bs[128*32];
    const int tid  = threadIdx.x;
    const int w    = tid >> 6, lane = tid & 63, quad = lane >> 4, l16 = lane & 15;
    const int wr   = w >> 1,  wc   = w & 1;
    const int m0   = blockIdx.x * 128, n0 = blockIdx.y * 128;
    const int arow = lane >> 2, acol = (lane & 3) * 8;

    const u16* ga = A  + (size_t)(m0 + w*32 + arow) * Kn + acol;
    const u16* gb = Bt + (size_t)(n0 + w*32 + arow) * Kn + acol;
    u16* la = As + (w*32) * 32;
    u16* lb = Bs + (w*32) * 32;

    f32x4 acc[4][4] = {};

    for (int k0 = 0; k0 < Kn; k0 += 32){
        __syncthreads();
        gld_lds16(ga + k0,                  la);
        gld_lds16(ga + k0 + (size_t)16*Kn,  la + 16*32);
        gld_lds16(gb + k0,                  lb);
        gld_lds16(gb + k0 + (size_t)16*Kn,  lb + 16*32);
        __syncthreads();
        bf16x8 af[4], bfr[4];
#pragma unroll
        for (int t = 0; t < 4; t++)
            af[t]  = *(const bf16x8*)(As + (wr*64 + t*16 + l16)*32 + quad*8);
#pragma unroll
        for (int t = 0; t < 4; t++)
            bfr[t] = *(const bf16x8*)(Bs + (wc*64 + t*16 + l16)*32 + quad*8);
#pragma unroll
        for (int tm = 0; tm < 4; tm++)
#pragma unroll
            for (int tn = 0; tn < 4; tn++)
                acc[tm][tn] = __builtin_amdgcn_mfma_f32_16x16x32_bf16(af[tm], bfr[tn], acc[tm][tn], 0, 0, 0);
    }

#pragma unroll
    for (int tn = 0; tn < 4; tn++){
        int col = n0 + wc*64 + tn*16 + l16;
        float bv = bias0[col];
#pragma unroll
        for (int tm = 0; tm < 4; tm++){
#pragma unroll
            for (int r = 0; r < 4; r++){
                int row = m0 + wr*64 + tm*16 + quad*4 + r;   // C/D: col=lane&15, row=quad*4+reg
                float v = acc[tm][tn][r] + bv;
                ((float*)out0)[(size_t)row * DMODEL + col] = v;
            }
        }
    }
}

// ---------------- flash attention v8 (best measured: 79.9us, 0 conflicts) ----------
// 4-wave blocks, Q-tile 128 (32 q-rows/wave), grid 1024 = 4 blocks/CU = 16 waves/CU,
// 4 independent barrier domains. Permuted V^T -> single conflict-free b128 PV read.
// QK^T transposed (A=K, B=Q, 16x16x32_bf16), P in registers, exp2-domain softmax
// without max-subtraction, K=32 PV via k-slot permutation.
// NOTE: __syncthreads() here is INTENTIONAL -- its implicit vmcnt(0) drain IS the
// synchronization that makes the freshly-staged dbuf half readable.
__global__ __launch_bounds__(256, 4) void flash_kern(
    const u16* __restrict__ Qb, const u16* __restrict__ Kb,
    const u16* __restrict__ Vt, u16* __restrict__ Ob)
{
    __shared__ alignas(16) u16 Ks[2][64*64];
    __shared__ alignas(16) u16 Vs[2][64*64];
    const int tid = threadIdx.x, w = tid >> 6, lane = tid & 63;
    const int quad = lane >> 4, l16 = lane & 15;
    const int q0 = blockIdx.x * 128;
    const int h  = blockIdx.y, b = blockIdx.z, g = h >> 2;

    const u16* Qg = Qb + (((size_t)b*NHEADS + h)*SEQ + q0 + w*32) * DKH;
    const u16* Kg = Kb + ((size_t)b*NGRP + g) * SEQ * DKH;   // [s][d] bf16
    const u16* Vg = Vt + ((size_t)b*NGRP + g) * DKH * SEQ;   // [d][s'] f16 (permuted)

    // staging: wave w covers rows w*16..w*16+15; lane -> (row lr, chunk lc), XOR swizzle
    const int lr = lane >> 3, lc = lane & 7;
    const int sw = lc ^ lr;
    const u16* gk0 = Kg + (size_t)(w*16 + lr) * DKH + sw*8;   // + kt*64*DKH
    const u16* gv0 = Vg + (size_t)(w*16 + lr) * SEQ + sw*8;   // + kt*64

    bf16x8 aq[2][2];   // [ks][nt] Q B-frags, kt-invariant (32 q-rows/wave)
#pragma unroll
    for (int nt = 0; nt < 2; nt++)
#pragma unroll
        for (int ks = 0; ks < 2; ks++)
            aq[ks][nt] = *(const bf16x8*)(Qg + (nt*16 + l16)*DKH + ks*32 + quad*8);

    float lsum[2] = {};
    f32x4 oa[2][4] = {};   // [nt(q)][dt(d)]

#define STAGE(buf, kt) do{                                                        \
        gld_lds16(gk0 + (size_t)(kt)*64*DKH,           Ks[buf] + (w*16)*64);      \
        gld_lds16(gk0 + (size_t)(kt)*64*DKH + 8*DKH,   Ks[buf] + (w*16+8)*64);    \
        gld_lds16(gv0 + (size_t)(kt)*64,               Vs[buf] + (w*16)*64);      \
        gld_lds16(gv0 + (size_t)(kt)*64 + (size_t)8*SEQ, Vs[buf] + (w*16+8)*64);  \
    }while(0)

    // Per 32-kv pair p (tiles kc=2p, 2p+1): QK^T + exp for both 16-tiles, pack f16;
    // PV: A = concat(pe,po); B = ONE b128 V^T read (chunk (4p+quad)^(l16&7)) thanks to
    // the global-side k-slot permutation -> one K=32 MFMA, zero bank conflicts.
#define COMPUTE(buf) do{                                                              \
        _Pragma("unroll")                                                             \
        for (int p = 0; p < 2; p++){                                                  \
            f16x4 pe[2], po[2];                                                       \
            _Pragma("unroll")                                                         \
            for (int hf = 0; hf < 2; hf++){                                           \
                const int kc = p*2 + hf;                                              \
                bf16x8 bk0 = *(const bf16x8*)(Ks[buf] + (kc*16 + l16)*64              \
                                              + ((quad     ^ (l16&7)) * 8));          \
                bf16x8 bk1 = *(const bf16x8*)(Ks[buf] + (kc*16 + l16)*64              \
                                              + (((4+quad) ^ (l16&7)) * 8));          \
                _Pragma("unroll")                                                     \
                for (int nt = 0; nt < 2; nt++){                                       \
                    f32x4 sa = {};                                                    \
                    sa = __builtin_amdgcn_mfma_f32_16x16x32_bf16(bk0, aq[0][nt], sa,0,0,0);\
                    sa = __builtin_amdgcn_mfma_f32_16x16x32_bf16(bk1, aq[1][nt], sa,0,0,0);\
                    float e0 = __builtin_amdgcn_exp2f(sa[0]);                         \
                    float e1 = __builtin_amdgcn_exp2f(sa[1]);                         \
                    float e2 = __builtin_amdgcn_exp2f(sa[2]);                         \
                    float e3 = __builtin_amdgcn_exp2f(sa[3]);                         \
                    lsum[nt] += (e0 + e1) + (e2 + e3);                                \
                    uint2 pk = make_uint2(                                            \
                        __builtin_bit_cast(uint32_t, __builtin_amdgcn_cvt_pkrtz(e0, e1)), \
                        __builtin_bit_cast(uint32_t, __builtin_amdgcn_cvt_pkrtz(e2, e3)));\
                    (hf ? po : pe)[nt] = __builtin_bit_cast(f16x4, pk);               \
                }                                                                     \
            }                                                                         \
            f16x8 pa8[2];                                                             \
            _Pragma("unroll")                                                         \
            for (int nt = 0; nt < 2; nt++)                                            \
                pa8[nt] = __builtin_shufflevector(pe[nt], po[nt], 0,1,2,3,4,5,6,7);   \
            _Pragma("unroll")                                                         \
            for (int dt = 0; dt < 4; dt++){                                           \
                f16x8 bv8 = *(const f16x8*)(Vs[buf] + (dt*16 + l16)*64                \
                             + (((4*p + quad) ^ (l16&7)) * 8));                       \
                _Pragma("unroll")                                                     \
                for (int nt = 0; nt < 2; nt++)                                        \
                    oa[nt][dt] = __builtin_amdgcn_mfma_f32_16x16x32_f16(              \
                        pa8[nt], bv8, oa[nt][dt], 0, 0, 0);                           \
            }                                                                         \
        }                                                                             \
    }while(0)

    STAGE(0, 0);
    __syncthreads();

    for (int kt2 = 0; kt2 < SEQ/128; ++kt2){
        int kt = kt2 * 2;
        STAGE(1, kt + 1);
        COMPUTE(0);
        __syncthreads();
        if (kt2 < SEQ/128 - 1) STAGE(0, kt + 2);
        COMPUTE(1);
        __syncthreads();
    }

    // lsum lives at lane l16 for q = nt*16+l16; reduce across quads, invert
#pragma unroll
    for (int nt = 0; nt < 2; nt++){
        float s = lsum[nt];
        s += __shfl_xor(s, 16, 64);
        s += __shfl_xor(s, 32, 64);
        lsum[nt] = 1.0f / s;
    }

    // oa D-layout: d = dt*16 + l16, q = nt*16 + quad*4 + r; inv from lane quad*4+r
#pragma unroll
    for (int nt = 0; nt < 2; nt++)
#pragma unroll
        for (int r = 0; r < 4; r++){
            float inv = __shfl(lsum[nt], quad*4 + r, 64);
            int q = q0 + w*32 + nt*16 + quad*4 + r;
#pragma unroll
            for (int dt = 0; dt < 4; dt++)
                Ob[((size_t)b*SEQ + q)*DMODEL + h*DKH + dt*16 + l16] = f2bf(oa[nt][dt][r] * inv);
        }
#undef STAGE
#undef COMPUTE
}

// ---------------- launcher ----------------

extern "C" void kernel_launch(void* const* d_in, const int* in_sizes, int n_in,
                              void* d_out, int out_size, void* d_ws, size_t ws_size,
                              hipStream_t stream)
{
    const float* x  = (const float*)d_in[0];
    const float* Wq = (const float*)d_in[1];
    const float* bq = (const float*)d_in[2];
    const float* Wk = (const float*)d_in[3];
    const float* bk = (const float*)d_in[4];
    const float* Wv = (const float*)d_in[5];
    const float* bv = (const float*)d_in[6];
    const float* Wo = (const float*)d_in[7];
    const float* bo = (const float*)d_in[8];

    uint8_t* p = (uint8_t*)d_ws;
    u16* xb  = (u16*)p; p += (size_t)MTOT*DMODEL*2;
    u16* WqT = (u16*)p; p += (size_t)DMODEL*DMODEL*2;          // } contiguous: Bt for
    u16* WkT = (u16*)p; p += (size_t)(NGRP*DKH)*DMODEL*2;      // } fused QKV GEMM
    u16* WvT = (u16*)p; p += (size_t)(NGRP*DKH)*DMODEL*2;
    u16* WoT = (u16*)p; p += (size_t)DMODEL*DMODEL*2;
    u16* Qb  = (u16*)p; p += (size_t)BATCH*NHEADS*SEQ*DKH*2;
    u16* Kb  = (u16*)p; p += (size_t)BATCH*NGRP*SEQ*DKH*2;
    u16* Vtb = (u16*)p; p += (size_t)BATCH*NGRP*DKH*SEQ*2;     // f16 bits, s-permuted
    u16* Ob  = (u16*)p; p += (size_t)MTOT*DMODEL*2;

    cvt_x_kern<<<MTOT*DMODEL/1024, 256, 0, stream>>>(x, xb);
    cvt_wT_all<<<dim3(160, 64), 256, 0, stream>>>(Wq, Wk, Wv, Wo, WqT, WkT, WvT, WoT);

    gemm_nt8<3><<<dim3(MTOT/256, 3072/256), 512, 0, stream>>>(
        xb, WqT, bq, bk, bv, Qb, Kb, Vtb, DMODEL);

    flash_kern<<<dim3(SEQ/128, NHEADS, BATCH), 256, 0, stream>>>(Qb, Kb, Vtb, Ob);

    gemm_nt<2><<<dim3(MTOT/128, DMODEL/128), 256, 0, stream>>>(
        Ob, WoT, bo, nullptr, nullptr, d_out, nullptr, nullptr, DMODEL);
}

// Round 8
// 325.464 us; speedup vs baseline: 1.1607x; 1.0158x over previous
//
#include <hip/hip_runtime.h>
#include <stdint.h>

#define DMODEL 2048
#define NHEADS 32
#define NGRP 8
#define DKH 64
#define BATCH 2
#define SEQ 2048
#define MTOT (BATCH*SEQ)   // 4096

typedef unsigned short u16;
typedef __bf16 bf16x8 __attribute__((ext_vector_type(8)));
typedef float f32x4 __attribute__((ext_vector_type(4)));
typedef _Float16 f16x4 __attribute__((ext_vector_type(4)));
typedef _Float16 f16x8 __attribute__((ext_vector_type(8)));

#define QSCALE 0.18033688011112042f   // (1/8) * log2(e): softmax in exp2 domain

__device__ __forceinline__ u16 f2bf(float f){
    uint32_t x = __float_as_uint(f);
    x += 0x7FFFu + ((x >> 16) & 1u);   // RNE; inputs are finite
    return (u16)(x >> 16);
}

__device__ __forceinline__ void gld_lds16(const u16* g, u16* l){
    __builtin_amdgcn_global_load_lds(
        (const __attribute__((address_space(1))) uint32_t*)g,
        (__attribute__((address_space(3))) uint32_t*)l, 16, 0, 0);
}

// inline-asm ds_read_b128: INVISIBLE to the compiler's alias analysis, so the
// loop-carried RAW vs global_load_lds does NOT trigger a compiler-inserted
// s_waitcnt vmcnt(0) before it (R7 post-mortem: that inserted drain is what kept
// every nt8 variant at ~1700 cyc/phase). Ordering is owned by the schedule's own
// explicit vmcnt/lgkmcnt + barriers (rule #18: lgkmcnt(0)+sched_barrier(0) before use).
__device__ __forceinline__ bf16x8 ds_readb128(const u16* p){
    bf16x8 r;
    asm volatile("ds_read_b128 %0, %1"
        : "=v"(r)
        : "v"((const __attribute__((address_space(3))) u16*)p));
    return r;
}

// ---------------- conversion kernels ----------------

__global__ void cvt_x_kern(const float* __restrict__ x, u16* __restrict__ xb){
    int i = (blockIdx.x * 256 + threadIdx.x) * 4;
    float4 v = *(const float4*)(x + i);
    uint32_t lo = (uint32_t)f2bf(v.x) | ((uint32_t)f2bf(v.y) << 16);
    uint32_t hi = (uint32_t)f2bf(v.z) | ((uint32_t)f2bf(v.w) << 16);
    *(uint2*)(xb + i) = make_uint2(lo, hi);
}

// all 4 weights [K=2048][N] fp32 -> WT [N][K] bf16, fused into one launch
__global__ void cvt_wT_all(const float* __restrict__ Wq, const float* __restrict__ Wk,
                           const float* __restrict__ Wv, const float* __restrict__ Wo,
                           u16* __restrict__ WqT, u16* __restrict__ WkT,
                           u16* __restrict__ WvT, u16* __restrict__ WoT){
    __shared__ float t[32][33];
    int bx = blockIdx.x;
    const float* W; u16* T; int N; int cx;
    if (bx < 64)      { W = Wq; T = WqT; N = 2048; cx = bx; }
    else if (bx < 80) { W = Wk; T = WkT; N = 512;  cx = bx - 64; }
    else if (bx < 96) { W = Wv; T = WvT; N = 512;  cx = bx - 80; }
    else              { W = Wo; T = WoT; N = 2048; cx = bx - 96; }
    int tx = threadIdx.x & 31, ty = threadIdx.x >> 5;
    int n0 = cx * 32, k0 = blockIdx.y * 32;
#pragma unroll
    for (int i = 0; i < 4; i++)
        t[ty*4+i][tx] = W[(size_t)(k0 + ty*4 + i) * N + n0 + tx];
    __syncthreads();
#pragma unroll
    for (int i = 0; i < 4; i++)
        T[(size_t)(n0 + ty*4 + i) * DMODEL + k0 + tx] = f2bf(t[tx][ty*4+i]);
}

// ---------------- v4: 8-phase 256x256 NT GEMM with asm ds_read (QKV only) -----------
// Structure = R7 (m201-faithful: BK=64, 2buf x 2kk, two raw barriers/phase, vmcnt(4)
// at ph4/ph8 only) + the one missing piece: frag reads via inline-asm ds_read_b128 so
// the compiler cannot insert vmcnt(0) drains for the loop-carried gld_lds->ds_read RAW.
// Ledger (re-verified): iter j computes tiles a=2j (buf0), b=2j+1 (buf1);
//   ph1 SA(1,1,b) ph2 SB(1,1,b) ph3 SA(0,0,c) ph4 SB(0,0,c)+VM4
//   ph5 SA(0,1,c) ph6 SB(0,1,c) ph7 SA(1,0,d) ph8 SB(1,0,d)+VM4   (c=2j+2, d=2j+3)
// RAW: each read phase's half staged 5-6 phases earlier, confirmed by a VM4 (2 loads/
// phase -> vmcnt(4) retires everything older than the newest 2 phases). WAR: a half's
// last ds_read drains at that phase's lgkmcnt(0), ordered before any overwrite-issue
// by the phase-end barrier. Tail stages clamp to tile 31 (keeps the ledger exact).
// LDS chunk XOR swizzle ^=((row>>1)&3) on global source + read addr: b128 reads 2-way
// max = free. K hardcoded 2048 (32 tiles).
template<int EPI>
__global__ __launch_bounds__(512, 2) void gemm_nt8(
    const u16* __restrict__ A, const u16* __restrict__ Bt,
    const float* __restrict__ bias0, const float* __restrict__ bias1, const float* __restrict__ bias2,
    void* __restrict__ out0, void* __restrict__ out1, void* __restrict__ out2, int Kn)
{
    __shared__ alignas(16) u16 Asub[2][2][8192];   // [buf][kk][256 rows x 4 chunks x 8] = 64 KiB
    __shared__ alignas(16) u16 Bsub[2][2][8192];   // 64 KiB
    const int tid = threadIdx.x, w = tid >> 6, lane = tid & 63;
    const int quad = lane >> 4, l16 = lane & 15;
    const int wm = w >> 2, wn = w & 3;

    // T1: XCD-bijective chunked swizzle (nwg % 8 == 0 for the grids used)
    int bid = blockIdx.y * gridDim.x + blockIdx.x;
    int nwg = gridDim.x * gridDim.y;
    int cpx = nwg >> 3;
    int sbid = (bid & 7) * cpx + (bid >> 3);
    int bx = sbid % gridDim.x, by = sbid / gridDim.x;
    const int m0 = bx * 256, n0 = by * 256;

    // staging: wave w: rows w*32 + {0,16} + (lane>>2), LDS chunk lane&3,
    // global chunk (lane&3) ^ ((lane>>3)&3)  [= (row>>1)&3 key]
    const u16* gAw = A  + (size_t)(m0 + w*32 + (lane >> 2)) * Kn + (((lane&3) ^ ((lane>>3)&3)) * 8);
    const u16* gBw = Bt + (size_t)(n0 + w*32 + (lane >> 2)) * Kn + (((lane&3) ^ ((lane>>3)&3)) * 8);

    const int swc = (quad ^ ((l16 >> 1) & 3)) * 8;   // read-side swizzled chunk (u16 units)

    bf16x8 af[8], bfr[2];
    f32x4 acc[8][4] = {};

#define SA(buf, kk, kt) do{ \
        gld_lds16(gAw + (kt)*64 + (kk)*32,                   &Asub[buf][kk][w*1024]);       \
        gld_lds16(gAw + (size_t)16*Kn + (kt)*64 + (kk)*32,   &Asub[buf][kk][w*1024 + 512]); \
    }while(0)
#define SB(buf, kk, kt) do{ \
        gld_lds16(gBw + (kt)*64 + (kk)*32,                   &Bsub[buf][kk][w*1024]);       \
        gld_lds16(gBw + (size_t)16*Kn + (kt)*64 + (kk)*32,   &Bsub[buf][kk][w*1024 + 512]); \
    }while(0)

#define NW  ((void)0)
#define VM4 asm volatile("s_waitcnt vmcnt(4)" ::: "memory")

#define PH(buf, np, kk, STG, WAIT) do{                                               \
        if (np == 0){                                                                \
            _Pragma("unroll")                                                        \
            for (int m = 0; m < 8; m++)                                              \
                af[m] = ds_readb128(&Asub[buf][kk][(wm*128 + m*16 + l16)*32 + swc]);  \
        }                                                                            \
        _Pragma("unroll")                                                            \
        for (int nl = 0; nl < 2; nl++)                                               \
            bfr[nl] = ds_readb128(&Bsub[buf][kk][(wn*64 + ((np)*2+nl)*16 + l16)*32 + swc]); \
        STG;                                                                         \
        WAIT;                                                                        \
        __builtin_amdgcn_s_barrier();                                                \
        asm volatile("s_waitcnt lgkmcnt(0)" ::: "memory");                           \
        __builtin_amdgcn_sched_barrier(0);                                           \
        __builtin_amdgcn_s_setprio(1);                                               \
        _Pragma("unroll")                                                            \
        for (int m = 0; m < 8; m++){                                                 \
            acc[m][(np)*2+0] = __builtin_amdgcn_mfma_f32_16x16x32_bf16(af[m], bfr[0], acc[m][(np)*2+0], 0,0,0); \
            acc[m][(np)*2+1] = __builtin_amdgcn_mfma_f32_16x16x32_bf16(af[m], bfr[1], acc[m][(np)*2+1], 0,0,0); \
        }                                                                            \
        __builtin_amdgcn_s_setprio(0);                                               \
        __builtin_amdgcn_s_barrier();                                                \
    }while(0)

    // prologue: tile0 (all 4 halves) + tile1 kk0 = 12 loads/wave; confirm tile0 (vmcnt 4)
    SA(0, 0, 0); SB(0, 0, 0);
    SA(0, 1, 0); SB(0, 1, 0);
    SA(1, 0, 1); SB(1, 0, 1);
    asm volatile("s_waitcnt vmcnt(4)" ::: "memory");
    __builtin_amdgcn_s_barrier();

    for (int j = 0; j < 16; j++){
        const int tb = 2*j + 1;
        const int tc = (2*j + 2 < 32) ? 2*j + 2 : 31;
        const int td = (2*j + 3 < 32) ? 2*j + 3 : 31;
        PH(0, 0, 0, SA(1, 1, tb), NW);
        PH(0, 1, 0, SB(1, 1, tb), NW);
        PH(0, 0, 1, SA(0, 0, tc), NW);
        PH(0, 1, 1, SB(0, 0, tc), VM4);
        PH(1, 0, 0, SA(0, 1, tc), NW);
        PH(1, 1, 0, SB(0, 1, tc), NW);
        PH(1, 0, 1, SA(1, 0, td), NW);
        PH(1, 1, 1, SB(1, 0, td), VM4);
    }

#undef PH
#undef SA
#undef SB
#undef NW
#undef VM4

    // ---------------- epilogue ----------------
#pragma unroll
    for (int n = 0; n < 4; n++){
        int col = n0 + wn*64 + n*16 + l16;
        float bv;
        if (EPI == 3) bv = (col < 2048) ? bias0[col] : (col < 2560) ? bias1[col-2048] : bias2[col-2560];
        else          bv = bias0[col];
#pragma unroll
        for (int m = 0; m < 8; m++){
#pragma unroll
            for (int r = 0; r < 4; r++){
                int row = m0 + wm*128 + m*16 + quad*4 + r;   // C/D: col=lane&15, row=quad*4+reg
                float v = acc[m][n][r] + bv;
                if (EPI == 3){
                    int b = row >> 11, s = row & (SEQ-1);
                    if (col < 2048){
                        int hh = col >> 6, d = col & 63;
                        ((u16*)out0)[(((size_t)b*NHEADS + hh)*SEQ + s)*DKH + d] = f2bf(v * QSCALE);
                    } else if (col < 2560){
                        int c = col - 2048, gg = c >> 6, d = c & 63;
                        ((u16*)out1)[(((size_t)b*NGRP + gg)*SEQ + s)*DKH + d] = f2bf(v);
                    } else {
                        int c = col - 2560, gg = c >> 6, d = c & 63;
                        int t = s & 31;   // flash PV k-slot permutation
                        int pos = (t < 16) ? (((t >> 2) << 3) | (t & 3))
                                           : ((((t & 15) >> 2) << 3) | 4 | (t & 3));
                        int sp = (s & ~31) | pos;
                        ((u16*)out2)[(((size_t)b*NGRP + gg)*DKH + d)*SEQ + sp] =
                            __builtin_bit_cast(u16, (_Float16)v);   // V in f16 for PV MFMA
                    }
                } else {
                    ((float*)out0)[(size_t)row * DMODEL + col] = v;
                }
            }
        }
    }
}

// ---------------- m97-style 128x128 NT GEMM (verified; O-proj) ----------------------
// C = A[M][K] * Bt[N][K]^T + bias. EPI 2: fp32 row-major + bias.
template<int EPI>
__global__ __launch_bounds__(256, 2) void gemm_nt(
    const u16* __restrict__ A, const u16* __restrict__ Bt,
    const float* __restrict__ bias0, const float* __restrict__ bias1, const float* __restrict__ bias2,
    void* __restrict__ out0, void* __restrict__ out1, void* __restrict__ out2, int Kn)
{
    __shared__ alignas(16) u16 As[128*32];
    __shared__ alignas(16) u16 Bs[128*32];
    const int tid  = threadIdx.x;
    const int w    = tid >> 6, lane = tid & 63, quad = lane >> 4, l16 = lane & 15;
    const int wr   = w >> 1,  wc   = w & 1;
    const int m0   = blockIdx.x * 128, n0 = blockIdx.y * 128;
    const int arow = lane >> 2, acol = (lane & 3) * 8;

    const u16* ga = A  + (size_t)(m0 + w*32 + arow) * Kn + acol;
    const u16* gb = Bt + (size_t)(n0 + w*32 + arow) * Kn + acol;
    u16* la = As + (w*32) * 32;
    u16* lb = Bs + (w*32) * 32;

    f32x4 acc[4][4] = {};

    for (int k0 = 0; k0 < Kn; k0 += 32){
        __syncthreads();
        gld_lds16(ga + k0,                  la);
        gld_lds16(ga + k0 + (size_t)16*Kn,  la + 16*32);
        gld_lds16(gb + k0,                  lb);
        gld_lds16(gb + k0 + (size_t)16*Kn,  lb + 16*32);
        __syncthreads();
        bf16x8 af[4], bfr[4];
#pragma unroll
        for (int t = 0; t < 4; t++)
            af[t]  = *(const bf16x8*)(As + (wr*64 + t*16 + l16)*32 + quad*8);
#pragma unroll
        for (int t = 0; t < 4; t++)
            bfr[t] = *(const bf16x8*)(Bs + (wc*64 + t*16 + l16)*32 + quad*8);
#pragma unroll
        for (int tm = 0; tm < 4; tm++)
#pragma unroll
            for (int tn = 0; tn < 4; tn++)
                acc[tm][tn] = __builtin_amdgcn_mfma_f32_16x16x32_bf16(af[tm], bfr[tn], acc[tm][tn], 0, 0, 0);
    }

#pragma unroll
    for (int tn = 0; tn < 4; tn++){
        int col = n0 + wc*64 + tn*16 + l16;
        float bv = bias0[col];
#pragma unroll
        for (int tm = 0; tm < 4; tm++){
#pragma unroll
            for (int r = 0; r < 4; r++){
                int row = m0 + wr*64 + tm*16 + quad*4 + r;   // C/D: col=lane&15, row=quad*4+reg
                float v = acc[tm][tn][r] + bv;
                ((float*)out0)[(size_t)row * DMODEL + col] = v;
            }
        }
    }
}

// ---------------- flash attention v8 (best measured: 79.9us, 0 conflicts) ----------
// 4-wave blocks, Q-tile 128 (32 q-rows/wave), grid 1024 = 4 blocks/CU = 16 waves/CU,
// 4 independent barrier domains. Permuted V^T -> single conflict-free b128 PV read.
// QK^T transposed (A=K, B=Q, 16x16x32_bf16), P in registers, exp2-domain softmax
// without max-subtraction, K=32 PV via k-slot permutation.
// __syncthreads() here is INTENTIONAL: its implicit vmcnt(0) drain IS the protocol.
__global__ __launch_bounds__(256, 4) void flash_kern(
    const u16* __restrict__ Qb, const u16* __restrict__ Kb,
    const u16* __restrict__ Vt, u16* __restrict__ Ob)
{
    __shared__ alignas(16) u16 Ks[2][64*64];
    __shared__ alignas(16) u16 Vs[2][64*64];
    const int tid = threadIdx.x, w = tid >> 6, lane = tid & 63;
    const int quad = lane >> 4, l16 = lane & 15;
    const int q0 = blockIdx.x * 128;
    const int h  = blockIdx.y, b = blockIdx.z, g = h >> 2;

    const u16* Qg = Qb + (((size_t)b*NHEADS + h)*SEQ + q0 + w*32) * DKH;
    const u16* Kg = Kb + ((size_t)b*NGRP + g) * SEQ * DKH;   // [s][d] bf16
    const u16* Vg = Vt + ((size_t)b*NGRP + g) * DKH * SEQ;   // [d][s'] f16 (permuted)

    // staging: wave w covers rows w*16..w*16+15; lane -> (row lr, chunk lc), XOR swizzle
    const int lr = lane >> 3, lc = lane & 7;
    const int sw = lc ^ lr;
    const u16* gk0 = Kg + (size_t)(w*16 + lr) * DKH + sw*8;   // + kt*64*DKH
    const u16* gv0 = Vg + (size_t)(w*16 + lr) * SEQ + sw*8;   // + kt*64

    bf16x8 aq[2][2];   // [ks][nt] Q B-frags, kt-invariant (32 q-rows/wave)
#pragma unroll
    for (int nt = 0; nt < 2; nt++)
#pragma unroll
        for (int ks = 0; ks < 2; ks++)
            aq[ks][nt] = *(const bf16x8*)(Qg + (nt*16 + l16)*DKH + ks*32 + quad*8);

    float lsum[2] = {};
    f32x4 oa[2][4] = {};   // [nt(q)][dt(d)]

#define STAGE(buf, kt) do{                                                        \
        gld_lds16(gk0 + (size_t)(kt)*64*DKH,           Ks[buf] + (w*16)*64);      \
        gld_lds16(gk0 + (size_t)(kt)*64*DKH + 8*DKH,   Ks[buf] + (w*16+8)*64);    \
        gld_lds16(gv0 + (size_t)(kt)*64,               Vs[buf] + (w*16)*64);      \
        gld_lds16(gv0 + (size_t)(kt)*64 + (size_t)8*SEQ, Vs[buf] + (w*16+8)*64);  \
    }while(0)

#define COMPUTE(buf) do{                                                              \
        _Pragma("unroll")                                                             \
        for (int p = 0; p < 2; p++){                                                  \
            f16x4 pe[2], po[2];                                                       \
            _Pragma("unroll")                                                         \
            for (int hf = 0; hf < 2; hf++){                                           \
                const int kc = p*2 + hf;                                              \
                bf16x8 bk0 = *(const bf16x8*)(Ks[buf] + (kc*16 + l16)*64              \
                                              + ((quad     ^ (l16&7)) * 8));          \
                bf16x8 bk1 = *(const bf16x8*)(Ks[buf] + (kc*16 + l16)*64              \
                                              + (((4+quad) ^ (l16&7)) * 8));          \
                _Pragma("unroll")                                                     \
                for (int nt = 0; nt < 2; nt++){                                       \
                    f32x4 sa = {};                                                    \
                    sa = __builtin_amdgcn_mfma_f32_16x16x32_bf16(bk0, aq[0][nt], sa,0,0,0);\
                    sa = __builtin_amdgcn_mfma_f32_16x16x32_bf16(bk1, aq[1][nt], sa,0,0,0);\
                    float e0 = __builtin_amdgcn_exp2f(sa[0]);                         \
                    float e1 = __builtin_amdgcn_exp2f(sa[1]);                         \
                    float e2 = __builtin_amdgcn_exp2f(sa[2]);                         \
                    float e3 = __builtin_amdgcn_exp2f(sa[3]);                         \
                    lsum[nt] += (e0 + e1) + (e2 + e3);                                \
                    uint2 pk = make_uint2(                                            \
                        __builtin_bit_cast(uint32_t, __builtin_amdgcn_cvt_pkrtz(e0, e1)), \
                        __builtin_bit_cast(uint32_t, __builtin_amdgcn_cvt_pkrtz(e2, e3)));\
                    (hf ? po : pe)[nt] = __builtin_bit_cast(f16x4, pk);               \
                }                                                                     \
            }                                                                         \
            f16x8 pa8[2];                                                             \
            _Pragma("unroll")                                                         \
            for (int nt = 0; nt < 2; nt++)                                            \
                pa8[nt] = __builtin_shufflevector(pe[nt], po[nt], 0,1,2,3,4,5,6,7);   \
            _Pragma("unroll")                                                         \
            for (int dt = 0; dt < 4; dt++){                                           \
                f16x8 bv8 = *(const f16x8*)(Vs[buf] + (dt*16 + l16)*64                \
                             + (((4*p + quad) ^ (l16&7)) * 8));                       \
                _Pragma("unroll")                                                     \
                for (int nt = 0; nt < 2; nt++)                                        \
                    oa[nt][dt] = __builtin_amdgcn_mfma_f32_16x16x32_f16(              \
                        pa8[nt], bv8, oa[nt][dt], 0, 0, 0);                           \
            }                                                                         \
        }                                                                             \
    }while(0)

    STAGE(0, 0);
    __syncthreads();

    for (int kt2 = 0; kt2 < SEQ/128; ++kt2){
        int kt = kt2 * 2;
        STAGE(1, kt + 1);
        COMPUTE(0);
        __syncthreads();
        if (kt2 < SEQ/128 - 1) STAGE(0, kt + 2);
        COMPUTE(1);
        __syncthreads();
    }

    // lsum lives at lane l16 for q = nt*16+l16; reduce across quads, invert
#pragma unroll
    for (int nt = 0; nt < 2; nt++){
        float s = lsum[nt];
        s += __shfl_xor(s, 16, 64);
        s += __shfl_xor(s, 32, 64);
        lsum[nt] = 1.0f / s;
    }

    // oa D-layout: d = dt*16 + l16, q = nt*16 + quad*4 + r; inv from lane quad*4+r
#pragma unroll
    for (int nt = 0; nt < 2; nt++)
#pragma unroll
        for (int r = 0; r < 4; r++){
            float inv = __shfl(lsum[nt], quad*4 + r, 64);
            int q = q0 + w*32 + nt*16 + quad*4 + r;
#pragma unroll
            for (int dt = 0; dt < 4; dt++)
                Ob[((size_t)b*SEQ + q)*DMODEL + h*DKH + dt*16 + l16] = f2bf(oa[nt][dt][r] * inv);
        }
#undef STAGE
#undef COMPUTE
}

// ---------------- launcher ----------------

extern "C" void kernel_launch(void* const* d_in, const int* in_sizes, int n_in,
                              void* d_out, int out_size, void* d_ws, size_t ws_size,
                              hipStream_t stream)
{
    const float* x  = (const float*)d_in[0];
    const float* Wq = (const float*)d_in[1];
    const float* bq = (const float*)d_in[2];
    const float* Wk = (const float*)d_in[3];
    const float* bk = (const float*)d_in[4];
    const float* Wv = (const float*)d_in[5];
    const float* bv = (const float*)d_in[6];
    const float* Wo = (const float*)d_in[7];
    const float* bo = (const float*)d_in[8];

    uint8_t* p = (uint8_t*)d_ws;
    u16* xb  = (u16*)p; p += (size_t)MTOT*DMODEL*2;
    u16* WqT = (u16*)p; p += (size_t)DMODEL*DMODEL*2;          // } contiguous: Bt for
    u16* WkT = (u16*)p; p += (size_t)(NGRP*DKH)*DMODEL*2;      // } fused QKV GEMM
    u16* WvT = (u16*)p; p += (size_t)(NGRP*DKH)*DMODEL*2;
    u16* WoT = (u16*)p; p += (size_t)DMODEL*DMODEL*2;
    u16* Qb  = (u16*)p; p += (size_t)BATCH*NHEADS*SEQ*DKH*2;
    u16* Kb  = (u16*)p; p += (size_t)BATCH*NGRP*SEQ*DKH*2;
    u16* Vtb = (u16*)p; p += (size_t)BATCH*NGRP*DKH*SEQ*2;     // f16 bits, s-permuted
    u16* Ob  = (u16*)p; p += (size_t)MTOT*DMODEL*2;

    cvt_x_kern<<<MTOT*DMODEL/1024, 256, 0, stream>>>(x, xb);
    cvt_wT_all<<<dim3(160, 64), 256, 0, stream>>>(Wq, Wk, Wv, Wo, WqT, WkT, WvT, WoT);

    gemm_nt8<3><<<dim3(MTOT/256, 3072/256), 512, 0, stream>>>(
        xb, WqT, bq, bk, bv, Qb, Kb, Vtb, DMODEL);

    flash_kern<<<dim3(SEQ/128, NHEADS, BATCH), 256, 0, stream>>>(Qb, Kb, Vtb, Ob);

    gemm_nt<2><<<dim3(MTOT/128, DMODEL/128), 256, 0, stream>>>(
        Ob, WoT, bo, nullptr, nullptr, d_out, nullptr, nullptr, DMODEL);
}